// Round 9
// baseline (186.927 us; speedup 1.0000x reference)
//
#include <hip/hip_runtime.h>
#include <hip/hip_bf16.h>
#include <math.h>

#define EMB  768
#define NH   12
#define HD   64
#define SEQ  2048
#define BATCH 2
#define NTOK 4096           // BATCH*SEQ

typedef __attribute__((ext_vector_type(8))) short short8;   // 8 bf16 = 4 VGPRs
typedef __attribute__((ext_vector_type(4))) float float4v;  // 4 fp32 acc

static __device__ __forceinline__ short f2bf(float f) {
    __hip_bfloat16 h = __float2bfloat16(f);
    return *reinterpret_cast<short*>(&h);
}

// async global->LDS, 16B per lane.  LDS dest = wave-uniform base + lane*16.
static __device__ __forceinline__ void gll16(const void* g, void* l) {
    __builtin_amdgcn_global_load_lds(
        (const __attribute__((address_space(1))) void*)g,
        (__attribute__((address_space(3))) void*)l, 16, 0, 0);
}

// heavy-first chunk decode tables (8-iter units then 4-iter units), uniform idx
__device__ const int BS8[16] = {1,2,3,3,4,4,5,5,5,6,6,6,7,7,7,7};
__device__ const int CS8[16] = {0,0,0,1,0,1,0,1,2,0,1,2,0,1,2,3};

// ---------------------------------------------------------------------------
// Kernel 0: cast x + 4 weights fp32 -> bf16 into workspace.
// ---------------------------------------------------------------------------
__global__ __launch_bounds__(256) void cast_kernel(
    const float* __restrict__ x,  const float* __restrict__ wq,
    const float* __restrict__ wk, const float* __restrict__ wv,
    const float* __restrict__ wo,
    __hip_bfloat16* __restrict__ xb,  __hip_bfloat16* __restrict__ wqb,
    __hip_bfloat16* __restrict__ wkb, __hip_bfloat16* __restrict__ wvb,
    __hip_bfloat16* __restrict__ wob)
{
    const size_t S0 = (size_t)NTOK * EMB;       // 3,145,728
    const size_t S1 = (size_t)EMB * EMB;        //   589,824
    size_t i = ((size_t)blockIdx.x * 256 + threadIdx.x) * 8;
    const float* src; __hip_bfloat16* dst; size_t off;
    if      (i < S0)            { src = x;  dst = xb;  off = i; }
    else if (i < S0 + S1)       { src = wq; dst = wqb; off = i - S0; }
    else if (i < S0 + 2 * S1)   { src = wk; dst = wkb; off = i - S0 - S1; }
    else if (i < S0 + 3 * S1)   { src = wv; dst = wvb; off = i - S0 - 2 * S1; }
    else                        { src = wo; dst = wob; off = i - S0 - 3 * S1; }
    float4 f0 = *(const float4*)&src[off];
    float4 f1 = *(const float4*)&src[off + 4];
    short8 o;
    o[0] = f2bf(f0.x); o[1] = f2bf(f0.y); o[2] = f2bf(f0.z); o[3] = f2bf(f0.w);
    o[4] = f2bf(f1.x); o[5] = f2bf(f1.y); o[6] = f2bf(f1.z); o[7] = f2bf(f1.w);
    *(short8*)&dst[off] = o;
}

// ---------------------------------------------------------------------------
// Kernel 1: fused QKV projection, bf16 MFMA, gll16 staging, XOR-swizzled LDS.
// 64x128 tiles -> 1152 blocks.  q scaled by 0.125*log2(e).
// Q/K: coalesced repack epilogue.  V: LDS transpose -> [bh][d][n].
// ---------------------------------------------------------------------------
__global__ __launch_bounds__(256) void qkv_mfma_kernel(
    const __hip_bfloat16* __restrict__ xb,
    const __hip_bfloat16* __restrict__ wqb, const float* __restrict__ bq,
    const __hip_bfloat16* __restrict__ wkb, const float* __restrict__ bk,
    const __hip_bfloat16* __restrict__ wvb, const float* __restrict__ bv,
    __hip_bfloat16* __restrict__ q, __hip_bfloat16* __restrict__ k,
    __hip_bfloat16* __restrict__ vT)
{
    __shared__ __align__(16) short SM[12288];     // As = SM (64x64), Bs = +4096 (128x64)
    short* As = SM;
    short* Bs = SM + 4096;
    const int t = threadIdx.x;
    const int w = t >> 6, lane = t & 63;
    const int col = lane & 15, quad = lane >> 4;
    const int wm = w >> 1, wn = w & 1;            // wave: 32 m-rows x 64 n-cols
    const int m0 = blockIdx.y * 64;
    const int mat = blockIdx.x / 6;               // 0=q 1=k 2=v
    const int jj0 = (blockIdx.x % 6) * 128;
    const short* X = (const short*)xb;
    const short* W = (const short*)((mat == 0) ? wqb : (mat == 1) ? wkb : wvb);
    const float* bias = (mat == 0) ? bq : (mat == 1) ? bk : bv;

    float4v acc[2][4];
    #pragma unroll
    for (int mi = 0; mi < 2; ++mi)
        #pragma unroll
        for (int ni = 0; ni < 4; ++ni) acc[mi][ni] = (float4v){0.f, 0.f, 0.f, 0.f};

    for (int kb = 0; kb < EMB; kb += 64) {
        #pragma unroll
        for (int c = 0; c < 2; ++c) {             // As: 512 chunks
            int I = w * 128 + c * 64 + lane;
            int row = I >> 3;
            int c8 = (I & 7) ^ (row & 7);
            gll16(X + (size_t)(m0 + row) * EMB + kb + c8 * 8,
                  &As[(w * 128 + c * 64) * 8]);
        }
        #pragma unroll
        for (int c = 0; c < 4; ++c) {             // Bs: 1024 chunks
            int I = w * 256 + c * 64 + lane;
            int row = I >> 3;
            int c8 = (I & 7) ^ (row & 7);
            gll16(W + (size_t)(jj0 + row) * EMB + kb + c8 * 8,
                  &Bs[(w * 256 + c * 64) * 8]);
        }
        __syncthreads();
        #pragma unroll
        for (int ks = 0; ks < 2; ++ks) {
            short8 a[2], b[4];
            #pragma unroll
            for (int mi = 0; mi < 2; ++mi) {
                int row = wm * 32 + mi * 16 + col;
                a[mi] = *(short8*)&As[row * 64 + (((ks * 4 + quad) ^ (row & 7)) * 8)];
            }
            #pragma unroll
            for (int ni = 0; ni < 4; ++ni) {
                int row = wn * 64 + ni * 16 + col;
                b[ni] = *(short8*)&Bs[row * 64 + (((ks * 4 + quad) ^ (row & 7)) * 8)];
            }
            #pragma unroll
            for (int mi = 0; mi < 2; ++mi)
                #pragma unroll
                for (int ni = 0; ni < 4; ++ni)
                    acc[mi][ni] = __builtin_amdgcn_mfma_f32_16x16x32_bf16(
                        a[mi], b[ni], acc[mi][ni], 0, 0, 0);
        }
        __syncthreads();
    }
    const int bi = m0 >> 11, n0g = m0 & (SEQ - 1);   // tile fits one batch
    if (mat != 2) {
        // q scale folds 1/8 and log2(e) (attn uses exp2)
        const float scale = (mat == 0) ? 0.125f * 1.44269504088896f : 1.0f;
        __hip_bfloat16* dstqk = (mat == 0) ? q : k;
        // C -> LDS [n_l(64)][gj_l(128)], chunk-XOR swizzle
        #pragma unroll
        for (int mi = 0; mi < 2; ++mi)
            #pragma unroll
            for (int ni = 0; ni < 4; ++ni) {
                int gj_l = wn * 64 + ni * 16 + col;     // 0..127
                float bsv = bias[jj0 + gj_l];
                #pragma unroll
                for (int r = 0; r < 4; ++r) {
                    int n_l = wm * 32 + mi * 16 + quad * 4 + r;   // 0..63
                    int cswz = (gj_l >> 3) ^ (n_l & 15);
                    SM[(n_l << 7) + (cswz << 3) + (gj_l & 7)] =
                        f2bf((acc[mi][ni][r] + bsv) * scale);
                }
            }
        __syncthreads();
        #pragma unroll
        for (int it = 0; it < 4; ++it) {
            int I = it * 256 + t;                 // 0..1023
            int n_l = I >> 4, c = I & 15;
            short8 val = *(short8*)&SM[(n_l << 7) + ((c ^ (n_l & 15)) << 3)];
            int gj = jj0 + c * 8;                 // 8-aligned within 768
            int h = gj >> 6, d0 = gj & 63;
            int gm = m0 + n_l;
            int bb = gm >> 11, n = gm & (SEQ - 1);
            *(short8*)&dstqk[(((size_t)bb * NH + h) * SEQ + n) * HD + d0] = val;
        }
    } else {
        // V: transpose via LDS [d_l(128)][n chunks(8)], chunk-XOR swizzle
        #pragma unroll
        for (int mi = 0; mi < 2; ++mi)
            #pragma unroll
            for (int ni = 0; ni < 4; ++ni) {
                int d_l = wn * 64 + ni * 16 + col;        // 0..127
                float bsv = bias[jj0 + d_l];
                #pragma unroll
                for (int r = 0; r < 4; ++r) {
                    int n_l = wm * 32 + mi * 16 + quad * 4 + r;   // 0..63
                    int cn = n_l >> 3;
                    SM[(d_l << 6) + (((cn ^ (d_l & 7))) << 3) + (n_l & 7)] =
                        f2bf(acc[mi][ni][r] + bsv);
                }
            }
        __syncthreads();
        #pragma unroll
        for (int it = 0; it < 4; ++it) {
            int I = it * 256 + t;                 // 0..1023
            int d_l = I >> 3, cn = I & 7;
            short8 val = *(short8*)&SM[(d_l << 6) + ((cn ^ (d_l & 7)) << 3)];
            int gj = jj0 + d_l;
            int h = gj >> 6, dd = gj & 63;
            *(short8*)&vT[(((size_t)bi * NH + h) * HD + dd) * SEQ + n0g + cn * 8] = val;
        }
    }
}

// ---------------------------------------------------------------------------
// Kernel 2: flash causal attention, 256 q-rows/block (4 waves x 64 rows =
// 4 m-tiles/wave): K/V LDS reads amortized over 2x rows vs r4; barrier iters
// per row halved.  Per-ni softmax slice keeps VGPRs low; Ps holds one 32-col
// half (stride 40, conflict-free b128).  KV chunks of 8 tiles, 480 blocks
// heavy-first; b<=1 single -> bf16 direct; b>=2 fp32 partials to slot c.
// Fully-masked tiles skip compute.  52KB LDS -> 3 blocks/CU.
// ---------------------------------------------------------------------------
__global__ __launch_bounds__(256) void attn_mfma_kernel(
    const __hip_bfloat16* __restrict__ qg, const __hip_bfloat16* __restrict__ kg,
    const __hip_bfloat16* __restrict__ vTg, __hip_bfloat16* __restrict__ ao,
    float* __restrict__ Osp, float* __restrict__ lsp)
{
    __shared__ __align__(16) short Ks[2][4096];
    __shared__ __align__(16) short Vt[2][4096];
    __shared__ __align__(16) short Ps[4][64 * 40];   // per-wave, 32-col half
    const int t = threadIdx.x;
    const int w = t >> 6, lane = t & 63;
    const int col = lane & 15, quad = lane >> 4;
    // ---- chunk decode (heavy-first): 20 chunk-units per bh ----
    const int id = blockIdx.x;
    const int bh = id % 24;
    const int x = id / 24;                     // 0..19
    int b, c;
    if (x < 16) { b = BS8[x]; c = CS8[x]; }
    else        { int i = x - 16; b = 2 * i; c = i; }
    const int kt0 = c * 8;
    const int tottiles = 4 * b + 4;
    const int niter = (tottiles - kt0 < 8) ? (tottiles - kt0) : 8;
    const bool single = (b <= 1);
    const int q0 = b * 256;
    const size_t base = (size_t)bh * SEQ * HD;
    const short* kp = (const short*)kg + base;
    const short* vp = (const short*)vTg + base;   // [d][n] per bh
    const short* qp = (const short*)qg + base;
    const int rw = q0 + w * 64;                // wave's 64-row band

    // Q fragments: 4 m-tiles per wave
    short8 qa[4][2];
    #pragma unroll
    for (int mi = 0; mi < 4; ++mi) {
        int qrow = rw + mi * 16 + col;
        #pragma unroll
        for (int ks = 0; ks < 2; ++ks)
            qa[mi][ks] = *(const short8*)&qp[(size_t)qrow * HD + ks * 32 + quad * 8];
    }
    float4v accO[4][4];
    float lacc[4][4];
    #pragma unroll
    for (int mi = 0; mi < 4; ++mi) {
        #pragma unroll
        for (int di = 0; di < 4; ++di) accO[mi][di] = (float4v){0.f, 0.f, 0.f, 0.f};
        #pragma unroll
        for (int r = 0; r < 4; ++r) lacc[mi][r] = 0.f;
    }

    // prologue: stage tile kt0 into buffer 0 (512 chunks per array, 2/lane)
    {
        const int k0 = kt0 * 64;
        #pragma unroll
        for (int cc = 0; cc < 2; ++cc) {
            int I = w * 128 + cc * 64 + lane;
            int row = I >> 3;
            int c8 = (I & 7) ^ (row & 7);
            gll16(kp + (size_t)(k0 + row) * HD + c8 * 8, &Ks[0][(w * 128 + cc * 64) * 8]);
            gll16(vp + (size_t)row * SEQ + k0 + c8 * 8, &Vt[0][(w * 128 + cc * 64) * 8]);
        }
    }

    for (int lk = 0; lk < niter; ++lk) {
        const int kt = kt0 + lk;
        const int cur = lk & 1;
        const int k0 = kt * 64;
        __syncthreads();
        if (lk + 1 < niter) {
            const int kn = k0 + 64;
            #pragma unroll
            for (int cc = 0; cc < 2; ++cc) {
                int I = w * 128 + cc * 64 + lane;
                int row = I >> 3;
                int c8 = (I & 7) ^ (row & 7);
                gll16(kp + (size_t)(kn + row) * HD + c8 * 8,
                      &Ks[cur ^ 1][(w * 128 + cc * 64) * 8]);
                gll16(vp + (size_t)row * SEQ + kn + c8 * 8,
                      &Vt[cur ^ 1][(w * 128 + cc * 64) * 8]);
            }
        }
        if (k0 > rw) continue;                 // fully masked for this wave
        const bool diag = (k0 == rw);
        const short* Kc = &Ks[cur][0];
        const short* Vc = &Vt[cur][0];
        short* Pw = &Ps[w][0];

        #pragma unroll
        for (int ni = 0; ni < 4; ++ni) {
            // S slice = Q @ K^T for 16 cols
            float4v s[4];
            #pragma unroll
            for (int mi = 0; mi < 4; ++mi) s[mi] = (float4v){0.f, 0.f, 0.f, 0.f};
            int krow = ni * 16 + col;
            #pragma unroll
            for (int ks = 0; ks < 2; ++ks) {
                short8 kf = *(short8*)&Kc[krow * 64 + (((ks * 4 + quad) ^ (krow & 7)) * 8)];
                #pragma unroll
                for (int mi = 0; mi < 4; ++mi)
                    s[mi] = __builtin_amdgcn_mfma_f32_16x16x32_bf16(
                        qa[mi][ks], kf, s[mi], 0, 0, 0);
            }
            // exp2 slice (+ mask on diagonal tile), lacc, P write (32-col half)
            if (diag) {
                int gcol = k0 + ni * 16 + col;
                #pragma unroll
                for (int mi = 0; mi < 4; ++mi)
                    #pragma unroll
                    for (int r = 0; r < 4; ++r) {
                        int grow = rw + mi * 16 + quad * 4 + r;
                        float p = (gcol > grow) ? 0.f : exp2f(s[mi][r]);
                        lacc[mi][r] += p;
                        Pw[(mi * 16 + quad * 4 + r) * 40 + (ni & 1) * 16 + col] = f2bf(p);
                    }
            } else {
                #pragma unroll
                for (int mi = 0; mi < 4; ++mi)
                    #pragma unroll
                    for (int r = 0; r < 4; ++r) {
                        float p = exp2f(s[mi][r]);
                        lacc[mi][r] += p;
                        Pw[(mi * 16 + quad * 4 + r) * 40 + (ni & 1) * 16 + col] = f2bf(p);
                    }
            }
            if (ni & 1) {
                // PV for this 32-col half (half = ni>>1)
                const int half = ni >> 1;
                short8 pa[4];
                #pragma unroll
                for (int mi = 0; mi < 4; ++mi)
                    pa[mi] = *(short8*)&Pw[(mi * 16 + col) * 40 + quad * 8];
                #pragma unroll
                for (int di = 0; di < 4; ++di) {
                    int vrow = di * 16 + col;
                    short8 vf = *(short8*)&Vc[vrow * 64 + (((half * 4 + quad) ^ (vrow & 7)) * 8)];
                    #pragma unroll
                    for (int mi = 0; mi < 4; ++mi)
                        accO[mi][di] = __builtin_amdgcn_mfma_f32_16x16x32_bf16(
                            pa[mi], vf, accO[mi][di], 0, 0, 0);
                }
            }
        }
    }

    // row-sum reduce across the 16 lanes of each quad-row group
    #pragma unroll
    for (int msk = 1; msk < 16; msk <<= 1)
        #pragma unroll
        for (int mi = 0; mi < 4; ++mi)
            #pragma unroll
            for (int r = 0; r < 4; ++r)
                lacc[mi][r] += __shfl_xor(lacc[mi][r], msk);

    const int bi = bh / NH, h = bh % NH;
    if (single) {
        #pragma unroll
        for (int mi = 0; mi < 4; ++mi)
            #pragma unroll
            for (int r = 0; r < 4; ++r) {
                float inv = 1.0f / lacc[mi][r];
                int n = rw + mi * 16 + quad * 4 + r;
                #pragma unroll
                for (int di = 0; di < 4; ++di)
                    ao[((size_t)bi * SEQ + n) * EMB + h * HD + di * 16 + col] =
                        __float2bfloat16(accO[mi][di][r] * inv);
            }
    } else {
        float* Os = Osp + (size_t)c * 2 * 1536 * EMB;
        float* ls = lsp + (size_t)c * 2 * 1536 * NH;
        #pragma unroll
        for (int mi = 0; mi < 4; ++mi)
            #pragma unroll
            for (int r = 0; r < 4; ++r) {
                int n = rw + mi * 16 + quad * 4 + r;   // >= 512
                int nn = n - 512;
                size_t rowb = ((size_t)bi * 1536 + nn) * EMB + h * HD;
                #pragma unroll
                for (int di = 0; di < 4; ++di)
                    Os[rowb + di * 16 + col] = accO[mi][di][r];
                if (col == 0)
                    ls[((size_t)bi * 1536 + nn) * NH + h] = lacc[mi][r];
            }
    }
}

// ---------------------------------------------------------------------------
// Kernel 3: combine partial slots for tokens n>=512 (nc = (qb>>1)+1 slots),
// normalize, -> ao bf16.
// ---------------------------------------------------------------------------
__global__ __launch_bounds__(256) void combine_kernel(
    const float* __restrict__ Osp, const float* __restrict__ lsp,
    __hip_bfloat16* __restrict__ ao)
{
    const size_t SLOT = (size_t)2 * 1536 * EMB;
    const size_t LSLOT = (size_t)2 * 1536 * NH;
    size_t e8 = ((size_t)blockIdx.x * 256 + threadIdx.x) * 8;  // < 2,359,296
    int u = e8 / EMB;                 // 0..3071 (bi*1536 + nn)
    int within = e8 % EMB;
    int h = within >> 6;
    int bi = u / 1536, nn = u % 1536;
    int n = 512 + nn;
    int qb = n >> 8;                  // 2..7
    int nc = (qb >> 1) + 1;           // 2..4
    float4 a0 = *(const float4*)&Osp[e8];
    float4 a1 = *(const float4*)&Osp[e8 + 4];
    float lsum = lsp[(size_t)u * NH + h];
    for (int cc = 1; cc < nc; ++cc) {
        const float* O = Osp + (size_t)cc * SLOT;
        float4 b0 = *(const float4*)&O[e8];
        float4 b1 = *(const float4*)&O[e8 + 4];
        a0.x += b0.x; a0.y += b0.y; a0.z += b0.z; a0.w += b0.w;
        a1.x += b1.x; a1.y += b1.y; a1.z += b1.z; a1.w += b1.w;
        lsum += lsp[(size_t)cc * LSLOT + (size_t)u * NH + h];
    }
    float inv = 1.0f / lsum;
    short8 o;
    o[0] = f2bf(a0.x * inv); o[1] = f2bf(a0.y * inv);
    o[2] = f2bf(a0.z * inv); o[3] = f2bf(a0.w * inv);
    o[4] = f2bf(a1.x * inv); o[5] = f2bf(a1.y * inv);
    o[6] = f2bf(a1.z * inv); o[7] = f2bf(a1.w * inv);
    *(short8*)&ao[((size_t)bi * SEQ + n) * EMB + within] = o;
}

// ---------------------------------------------------------------------------
// Kernel 4: output projection, 64x64 tiles -> 768 blocks (3.0 blocks/CU).
// gll16 staging, XOR swizzle.
// ---------------------------------------------------------------------------
__global__ __launch_bounds__(256) void out_proj_mfma_kernel(
    const __hip_bfloat16* __restrict__ a, const __hip_bfloat16* __restrict__ wob,
    const float* __restrict__ bias, float* __restrict__ out)
{
    __shared__ __align__(16) short As[64 * 64];
    __shared__ __align__(16) short Bs[64 * 64];
    const int t = threadIdx.x;
    const int w = t >> 6, lane = t & 63;
    const int col = lane & 15, quad = lane >> 4;
    const int wm = w >> 1, wn = w & 1;            // wave: 32 m x 32 n
    const int m0 = blockIdx.y * 64;
    const int n0 = blockIdx.x * 64;
    const short* A = (const short*)a;
    const short* W = (const short*)wob;

    float4v acc[2][2];
    #pragma unroll
    for (int mi = 0; mi < 2; ++mi)
        #pragma unroll
        for (int ni = 0; ni < 2; ++ni) acc[mi][ni] = (float4v){0.f, 0.f, 0.f, 0.f};

    for (int kb = 0; kb < EMB; kb += 64) {
        #pragma unroll
        for (int c = 0; c < 2; ++c) {
            int I = w * 128 + c * 64 + lane;      // 0..511
            int row = I >> 3;
            int c8 = (I & 7) ^ (row & 7);
            gll16(A + (size_t)(m0 + row) * EMB + kb + c8 * 8,
                  &As[(w * 128 + c * 64) * 8]);
            gll16(W + (size_t)(n0 + row) * EMB + kb + c8 * 8,
                  &Bs[(w * 128 + c * 64) * 8]);
        }
        __syncthreads();
        #pragma unroll
        for (int ks = 0; ks < 2; ++ks) {
            short8 av[2], bv[2];
            #pragma unroll
            for (int mi = 0; mi < 2; ++mi) {
                int row = wm * 32 + mi * 16 + col;
                av[mi] = *(short8*)&As[row * 64 + (((ks * 4 + quad) ^ (row & 7)) * 8)];
            }
            #pragma unroll
            for (int ni = 0; ni < 2; ++ni) {
                int row = wn * 32 + ni * 16 + col;
                bv[ni] = *(short8*)&Bs[row * 64 + (((ks * 4 + quad) ^ (row & 7)) * 8)];
            }
            #pragma unroll
            for (int mi = 0; mi < 2; ++mi)
                #pragma unroll
                for (int ni = 0; ni < 2; ++ni)
                    acc[mi][ni] = __builtin_amdgcn_mfma_f32_16x16x32_bf16(
                        av[mi], bv[ni], acc[mi][ni], 0, 0, 0);
        }
        __syncthreads();
    }
    #pragma unroll
    for (int mi = 0; mi < 2; ++mi)
        #pragma unroll
        for (int ni = 0; ni < 2; ++ni) {
            int gj = n0 + wn * 32 + ni * 16 + col;
            float bsv = bias[gj];
            #pragma unroll
            for (int r = 0; r < 4; ++r) {
                int gm = m0 + wm * 32 + mi * 16 + quad * 4 + r;
                out[(size_t)gm * EMB + gj] = acc[mi][ni][r] + bsv;
            }
        }
}

extern "C" void kernel_launch(void* const* d_in, const int* in_sizes, int n_in,
                              void* d_out, int out_size, void* d_ws, size_t ws_size,
                              hipStream_t stream) {
    const float* x  = (const float*)d_in[0];
    const float* wq = (const float*)d_in[1];
    const float* bq = (const float*)d_in[2];
    const float* wk = (const float*)d_in[3];
    const float* bk = (const float*)d_in[4];
    const float* wv = (const float*)d_in[5];
    const float* bv = (const float*)d_in[6];
    const float* wo = (const float*)d_in[7];
    const float* bo = (const float*)d_in[8];
    float* out = (float*)d_out;

    const size_t TOK = (size_t)NTOK * EMB;     // 3,145,728
    const size_t WSZ = (size_t)EMB * EMB;      //   589,824
    __hip_bfloat16* xb  = (__hip_bfloat16*)d_ws;
    __hip_bfloat16* wqb = xb  + TOK;
    __hip_bfloat16* wkb = wqb + WSZ;
    __hip_bfloat16* wvb = wkb + WSZ;
    __hip_bfloat16* wob = wvb + WSZ;
    __hip_bfloat16* qb  = wob + WSZ;
    __hip_bfloat16* kb  = qb  + TOK;
    __hip_bfloat16* vTb = kb  + TOK;
    __hip_bfloat16* aob = vTb + TOK;
    // fp32 partial slots (4 chunk slots) for tokens >= 512
    float* Osp = (float*)(aob + TOK);                       // 4*2*1536*768 fp32
    float* lsp = Osp + (size_t)4 * 2 * 1536 * EMB;          // 4*2*1536*12 fp32

    cast_kernel<<<2688, 256, 0, stream>>>(x, wq, wk, wv, wo, xb, wqb, wkb, wvb, wob);
    qkv_mfma_kernel<<<dim3(18, 64), 256, 0, stream>>>(xb, wqb, bq, wkb, bk, wvb, bv,
                                                      qb, kb, vTb);
    attn_mfma_kernel<<<480, 256, 0, stream>>>(qb, kb, vTb, aob, Osp, lsp);
    combine_kernel<<<1152, 256, 0, stream>>>(Osp, lsp, aob);
    out_proj_mfma_kernel<<<dim3(12, 64), 256, 0, stream>>>(aob, wob, bo, out);
}

// Round 10
// 160.604 us; speedup vs baseline: 1.1639x; 1.1639x over previous
//
#include <hip/hip_runtime.h>
#include <hip/hip_bf16.h>
#include <math.h>

#define EMB  768
#define NH   12
#define HD   64
#define SEQ  2048
#define BATCH 2
#define NTOK 4096           // BATCH*SEQ

typedef __attribute__((ext_vector_type(8))) short short8;   // 8 bf16 = 4 VGPRs
typedef __attribute__((ext_vector_type(4))) float float4v;  // 4 fp32 acc

static __device__ __forceinline__ short f2bf(float f) {
    __hip_bfloat16 h = __float2bfloat16(f);
    return *reinterpret_cast<short*>(&h);
}

// async global->LDS, 16B per lane.  LDS dest = wave-uniform base + lane*16.
static __device__ __forceinline__ void gll16(const void* g, void* l) {
    __builtin_amdgcn_global_load_lds(
        (const __attribute__((address_space(1))) void*)g,
        (__attribute__((address_space(3))) void*)l, 16, 0, 0);
}

// heavy-first chunk-unit tables: 40 units/bh of (q-block b, chunk c), 8-tile
// chunks.  niter = min(8, 2b+2-8c).  Ordered 8-iter units first, then 6,4,2.
__device__ const unsigned char UB[40] = {
    3,4,5,6,7,8,9,10,11,12,13,14,15,          // c0 full-8
    7,8,9,10,11,12,13,14,15,                  // c1 full-8
    11,12,13,14,15,                           // c2 full-8
    15,                                       // c3 full-8
    2,6,10,14,                                // 6-iter
    1,5,9,13,                                 // 4-iter
    0,4,8,12};                                // 2-iter
__device__ const unsigned char UC[40] = {
    0,0,0,0,0,0,0,0,0,0,0,0,0,
    1,1,1,1,1,1,1,1,1,
    2,2,2,2,2,
    3,
    0,1,2,3,
    0,1,2,3,
    0,1,2,3};

// ---------------------------------------------------------------------------
// Kernel 0: cast x + 4 weights fp32 -> bf16 into workspace.
// ---------------------------------------------------------------------------
__global__ __launch_bounds__(256) void cast_kernel(
    const float* __restrict__ x,  const float* __restrict__ wq,
    const float* __restrict__ wk, const float* __restrict__ wv,
    const float* __restrict__ wo,
    __hip_bfloat16* __restrict__ xb,  __hip_bfloat16* __restrict__ wqb,
    __hip_bfloat16* __restrict__ wkb, __hip_bfloat16* __restrict__ wvb,
    __hip_bfloat16* __restrict__ wob)
{
    const size_t S0 = (size_t)NTOK * EMB;       // 3,145,728
    const size_t S1 = (size_t)EMB * EMB;        //   589,824
    size_t i = ((size_t)blockIdx.x * 256 + threadIdx.x) * 8;
    const float* src; __hip_bfloat16* dst; size_t off;
    if      (i < S0)            { src = x;  dst = xb;  off = i; }
    else if (i < S0 + S1)       { src = wq; dst = wqb; off = i - S0; }
    else if (i < S0 + 2 * S1)   { src = wk; dst = wkb; off = i - S0 - S1; }
    else if (i < S0 + 3 * S1)   { src = wv; dst = wvb; off = i - S0 - 2 * S1; }
    else                        { src = wo; dst = wob; off = i - S0 - 3 * S1; }
    float4 f0 = *(const float4*)&src[off];
    float4 f1 = *(const float4*)&src[off + 4];
    short8 o;
    o[0] = f2bf(f0.x); o[1] = f2bf(f0.y); o[2] = f2bf(f0.z); o[3] = f2bf(f0.w);
    o[4] = f2bf(f1.x); o[5] = f2bf(f1.y); o[6] = f2bf(f1.z); o[7] = f2bf(f1.w);
    *(short8*)&dst[off] = o;
}

// ---------------------------------------------------------------------------
// Kernel 1: fused QKV projection, bf16 MFMA, gll16 staging, XOR-swizzled LDS.
// 64x128 tiles -> 1152 blocks.  q scaled by 0.125*log2(e).
// Q/K: coalesced repack epilogue.  V: LDS transpose -> [bh][d][n].
// ---------------------------------------------------------------------------
__global__ __launch_bounds__(256) void qkv_mfma_kernel(
    const __hip_bfloat16* __restrict__ xb,
    const __hip_bfloat16* __restrict__ wqb, const float* __restrict__ bq,
    const __hip_bfloat16* __restrict__ wkb, const float* __restrict__ bk,
    const __hip_bfloat16* __restrict__ wvb, const float* __restrict__ bv,
    __hip_bfloat16* __restrict__ q, __hip_bfloat16* __restrict__ k,
    __hip_bfloat16* __restrict__ vT)
{
    __shared__ __align__(16) short SM[12288];     // As = SM (64x64), Bs = +4096 (128x64)
    short* As = SM;
    short* Bs = SM + 4096;
    const int t = threadIdx.x;
    const int w = t >> 6, lane = t & 63;
    const int col = lane & 15, quad = lane >> 4;
    const int wm = w >> 1, wn = w & 1;            // wave: 32 m-rows x 64 n-cols
    const int m0 = blockIdx.y * 64;
    const int mat = blockIdx.x / 6;               // 0=q 1=k 2=v
    const int jj0 = (blockIdx.x % 6) * 128;
    const short* X = (const short*)xb;
    const short* W = (const short*)((mat == 0) ? wqb : (mat == 1) ? wkb : wvb);
    const float* bias = (mat == 0) ? bq : (mat == 1) ? bk : bv;

    float4v acc[2][4];
    #pragma unroll
    for (int mi = 0; mi < 2; ++mi)
        #pragma unroll
        for (int ni = 0; ni < 4; ++ni) acc[mi][ni] = (float4v){0.f, 0.f, 0.f, 0.f};

    for (int kb = 0; kb < EMB; kb += 64) {
        #pragma unroll
        for (int c = 0; c < 2; ++c) {             // As: 512 chunks
            int I = w * 128 + c * 64 + lane;
            int row = I >> 3;
            int c8 = (I & 7) ^ (row & 7);
            gll16(X + (size_t)(m0 + row) * EMB + kb + c8 * 8,
                  &As[(w * 128 + c * 64) * 8]);
        }
        #pragma unroll
        for (int c = 0; c < 4; ++c) {             // Bs: 1024 chunks
            int I = w * 256 + c * 64 + lane;
            int row = I >> 3;
            int c8 = (I & 7) ^ (row & 7);
            gll16(W + (size_t)(jj0 + row) * EMB + kb + c8 * 8,
                  &Bs[(w * 256 + c * 64) * 8]);
        }
        __syncthreads();
        #pragma unroll
        for (int ks = 0; ks < 2; ++ks) {
            short8 a[2], b[4];
            #pragma unroll
            for (int mi = 0; mi < 2; ++mi) {
                int row = wm * 32 + mi * 16 + col;
                a[mi] = *(short8*)&As[row * 64 + (((ks * 4 + quad) ^ (row & 7)) * 8)];
            }
            #pragma unroll
            for (int ni = 0; ni < 4; ++ni) {
                int row = wn * 64 + ni * 16 + col;
                b[ni] = *(short8*)&Bs[row * 64 + (((ks * 4 + quad) ^ (row & 7)) * 8)];
            }
            #pragma unroll
            for (int mi = 0; mi < 2; ++mi)
                #pragma unroll
                for (int ni = 0; ni < 4; ++ni)
                    acc[mi][ni] = __builtin_amdgcn_mfma_f32_16x16x32_bf16(
                        a[mi], b[ni], acc[mi][ni], 0, 0, 0);
        }
        __syncthreads();
    }
    const int bi = m0 >> 11, n0g = m0 & (SEQ - 1);   // tile fits one batch
    if (mat != 2) {
        // q scale folds 1/8 and log2(e) (attn uses exp2)
        const float scale = (mat == 0) ? 0.125f * 1.44269504088896f : 1.0f;
        __hip_bfloat16* dstqk = (mat == 0) ? q : k;
        // C -> LDS [n_l(64)][gj_l(128)], chunk-XOR swizzle
        #pragma unroll
        for (int mi = 0; mi < 2; ++mi)
            #pragma unroll
            for (int ni = 0; ni < 4; ++ni) {
                int gj_l = wn * 64 + ni * 16 + col;     // 0..127
                float bsv = bias[jj0 + gj_l];
                #pragma unroll
                for (int r = 0; r < 4; ++r) {
                    int n_l = wm * 32 + mi * 16 + quad * 4 + r;   // 0..63
                    int cswz = (gj_l >> 3) ^ (n_l & 15);
                    SM[(n_l << 7) + (cswz << 3) + (gj_l & 7)] =
                        f2bf((acc[mi][ni][r] + bsv) * scale);
                }
            }
        __syncthreads();
        #pragma unroll
        for (int it = 0; it < 4; ++it) {
            int I = it * 256 + t;                 // 0..1023
            int n_l = I >> 4, c = I & 15;
            short8 val = *(short8*)&SM[(n_l << 7) + ((c ^ (n_l & 15)) << 3)];
            int gj = jj0 + c * 8;                 // 8-aligned within 768
            int h = gj >> 6, d0 = gj & 63;
            int gm = m0 + n_l;
            int bb = gm >> 11, n = gm & (SEQ - 1);
            *(short8*)&dstqk[(((size_t)bb * NH + h) * SEQ + n) * HD + d0] = val;
        }
    } else {
        // V: transpose via LDS [d_l(128)][n chunks(8)], chunk-XOR swizzle
        #pragma unroll
        for (int mi = 0; mi < 2; ++mi)
            #pragma unroll
            for (int ni = 0; ni < 4; ++ni) {
                int d_l = wn * 64 + ni * 16 + col;        // 0..127
                float bsv = bias[jj0 + d_l];
                #pragma unroll
                for (int r = 0; r < 4; ++r) {
                    int n_l = wm * 32 + mi * 16 + quad * 4 + r;   // 0..63
                    int cn = n_l >> 3;
                    SM[(d_l << 6) + (((cn ^ (d_l & 7))) << 3) + (n_l & 7)] =
                        f2bf(acc[mi][ni][r] + bsv);
                }
            }
        __syncthreads();
        #pragma unroll
        for (int it = 0; it < 4; ++it) {
            int I = it * 256 + t;                 // 0..1023
            int d_l = I >> 3, cn = I & 7;
            short8 val = *(short8*)&SM[(d_l << 6) + ((cn ^ (d_l & 7)) << 3)];
            int gj = jj0 + d_l;
            int h = gj >> 6, dd = gj & 63;
            *(short8*)&vT[(((size_t)bi * NH + h) * HD + dd) * SEQ + n0g + cn * 8] = val;
        }
    }
}

// ---------------------------------------------------------------------------
// Kernel 2: flash causal attention (r8-proven iteration structure).  128
// q-rows/block, 4 waves x 32 rows; LDS-staged K/V via gll16, double-buffered.
// Static-max softmax via exp2.  KV chunks of EIGHT tiles -> 40 units/bh,
// 960 blocks (3.75/CU), heavy-first table.  b<=3 single chunk -> bf16 direct;
// b>=4 fp32 partials to slot c (tokens n>=512, up to 4 slots).
// ---------------------------------------------------------------------------
__global__ __launch_bounds__(256) void attn_mfma_kernel(
    const __hip_bfloat16* __restrict__ qg, const __hip_bfloat16* __restrict__ kg,
    const __hip_bfloat16* __restrict__ vTg, __hip_bfloat16* __restrict__ ao,
    float* __restrict__ Osp, float* __restrict__ lsp)
{
    __shared__ __align__(16) short Ks[2][64 * 64];
    __shared__ __align__(16) short Vt[2][64 * 64];
    __shared__ __align__(16) short Ps[4][32][72];
    const int t = threadIdx.x;
    const int w = t >> 6, lane = t & 63;
    const int col = lane & 15, quad = lane >> 4;
    // ---- chunk decode (heavy-first): 40 chunk-units per bh ----
    const int id = blockIdx.x;
    const int bh = id % 24;
    const int x = id / 24;                     // 0..39
    const int b = UB[x], c = UC[x];
    const int kt0 = c * 8;
    const int tottiles = 2 * b + 2;
    const int niter = (tottiles - kt0 < 8) ? (tottiles - kt0) : 8;
    const bool single = (b <= 3);
    const int q0 = b * 128;
    const size_t base = (size_t)bh * SEQ * HD;
    const short* kp = (const short*)kg + base;
    const short* vp = (const short*)vTg + base;   // [d][n] per bh
    const short* qp = (const short*)qg + base;

    // wave w owns m-tiles 2w, 2w+1 (rows q0 + (2w+mi)*16 ..)
    short8 qa[2][2];
    #pragma unroll
    for (int mi = 0; mi < 2; ++mi) {
        int qrow = q0 + (2 * w + mi) * 16 + col;
        #pragma unroll
        for (int ks = 0; ks < 2; ++ks)
            qa[mi][ks] = *(const short8*)&qp[(size_t)qrow * HD + ks * 32 + quad * 8];
    }
    float4v accO[2][4];
    float lacc[2][4];
    #pragma unroll
    for (int mi = 0; mi < 2; ++mi) {
        #pragma unroll
        for (int di = 0; di < 4; ++di) accO[mi][di] = (float4v){0.f, 0.f, 0.f, 0.f};
        #pragma unroll
        for (int r = 0; r < 4; ++r) lacc[mi][r] = 0.f;
    }

    // prologue: stage tile kt0 into buffer 0 (512 chunks per array, 2/lane)
    {
        const int k0 = kt0 * 64;
        #pragma unroll
        for (int cc = 0; cc < 2; ++cc) {
            int I = w * 128 + cc * 64 + lane;
            int row = I >> 3;
            int c8 = (I & 7) ^ (row & 7);
            gll16(kp + (size_t)(k0 + row) * HD + c8 * 8, &Ks[0][(w * 128 + cc * 64) * 8]);
            gll16(vp + (size_t)row * SEQ + k0 + c8 * 8, &Vt[0][(w * 128 + cc * 64) * 8]);
        }
    }

    for (int lk = 0; lk < niter; ++lk) {
        const int kt = kt0 + lk;
        const int cur = lk & 1;
        const int k0 = kt * 64;
        __syncthreads();
        if (lk + 1 < niter) {
            const int kn = k0 + 64;
            #pragma unroll
            for (int cc = 0; cc < 2; ++cc) {
                int I = w * 128 + cc * 64 + lane;
                int row = I >> 3;
                int c8 = (I & 7) ^ (row & 7);
                gll16(kp + (size_t)(kn + row) * HD + c8 * 8,
                      &Ks[cur ^ 1][(w * 128 + cc * 64) * 8]);
                gll16(vp + (size_t)row * SEQ + kn + c8 * 8,
                      &Vt[cur ^ 1][(w * 128 + cc * 64) * 8]);
            }
        }
        const short* Kc = &Ks[cur][0];
        const short* Vc = &Vt[cur][0];

        float4v s[2][4];
        #pragma unroll
        for (int mi = 0; mi < 2; ++mi)
            #pragma unroll
            for (int ni = 0; ni < 4; ++ni) s[mi][ni] = (float4v){0.f, 0.f, 0.f, 0.f};
        #pragma unroll
        for (int ks = 0; ks < 2; ++ks)
            #pragma unroll
            for (int ni = 0; ni < 4; ++ni) {
                int row = ni * 16 + col;
                short8 kf = *(short8*)&Kc[row * 64 + (((ks * 4 + quad) ^ (row & 7)) * 8)];
                #pragma unroll
                for (int mi = 0; mi < 2; ++mi)
                    s[mi][ni] = __builtin_amdgcn_mfma_f32_16x16x32_bf16(
                        qa[mi][ks], kf, s[mi][ni], 0, 0, 0);
            }

        // p = exp2(s)  (log2e pre-folded into q); diagonal-region tiles masked
        if (k0 >= q0) {
            #pragma unroll
            for (int mi = 0; mi < 2; ++mi)
                #pragma unroll
                for (int ni = 0; ni < 4; ++ni) {
                    int gcol = k0 + ni * 16 + col;
                    #pragma unroll
                    for (int r = 0; r < 4; ++r) {
                        int grow = q0 + (2 * w + mi) * 16 + quad * 4 + r;
                        s[mi][ni][r] = (gcol > grow) ? 0.f : exp2f(s[mi][ni][r]);
                    }
                }
        } else {
            #pragma unroll
            for (int mi = 0; mi < 2; ++mi)
                #pragma unroll
                for (int ni = 0; ni < 4; ++ni)
                    #pragma unroll
                    for (int r = 0; r < 4; ++r)
                        s[mi][ni][r] = exp2f(s[mi][ni][r]);
        }
        #pragma unroll
        for (int mi = 0; mi < 2; ++mi)
            #pragma unroll
            for (int r = 0; r < 4; ++r)
                lacc[mi][r] += (s[mi][0][r] + s[mi][1][r]) + (s[mi][2][r] + s[mi][3][r]);

        // P (C-layout) -> per-wave LDS -> A-layout frags (same-wave, no barrier)
        #pragma unroll
        for (int mi = 0; mi < 2; ++mi)
            #pragma unroll
            for (int ni = 0; ni < 4; ++ni)
                #pragma unroll
                for (int r = 0; r < 4; ++r)
                    Ps[w][mi * 16 + quad * 4 + r][ni * 16 + col] = f2bf(s[mi][ni][r]);
        short8 pa[2][2];
        #pragma unroll
        for (int mi = 0; mi < 2; ++mi)
            #pragma unroll
            for (int ks = 0; ks < 2; ++ks)
                pa[mi][ks] = *(short8*)&Ps[w][mi * 16 + col][ks * 32 + quad * 8];

        #pragma unroll
        for (int ks = 0; ks < 2; ++ks)
            #pragma unroll
            for (int di = 0; di < 4; ++di) {
                int row = di * 16 + col;
                short8 vf = *(short8*)&Vc[row * 64 + (((ks * 4 + quad) ^ (row & 7)) * 8)];
                #pragma unroll
                for (int mi = 0; mi < 2; ++mi)
                    accO[mi][di] = __builtin_amdgcn_mfma_f32_16x16x32_bf16(
                        pa[mi][ks], vf, accO[mi][di], 0, 0, 0);
            }
    }

    // row-sum reduce across the 16 lanes of each quad-row group
    #pragma unroll
    for (int msk = 1; msk < 16; msk <<= 1)
        #pragma unroll
        for (int mi = 0; mi < 2; ++mi)
            #pragma unroll
            for (int r = 0; r < 4; ++r)
                lacc[mi][r] += __shfl_xor(lacc[mi][r], msk);

    const int bi = bh / NH, h = bh % NH;
    if (single) {
        #pragma unroll
        for (int mi = 0; mi < 2; ++mi)
            #pragma unroll
            for (int r = 0; r < 4; ++r) {
                float inv = 1.0f / lacc[mi][r];
                int n = q0 + (2 * w + mi) * 16 + quad * 4 + r;
                #pragma unroll
                for (int di = 0; di < 4; ++di)
                    ao[((size_t)bi * SEQ + n) * EMB + h * HD + di * 16 + col] =
                        __float2bfloat16(accO[mi][di][r] * inv);
            }
    } else {
        float* Os = Osp + (size_t)c * 2 * 1536 * EMB;
        float* ls = lsp + (size_t)c * 2 * 1536 * NH;
        #pragma unroll
        for (int mi = 0; mi < 2; ++mi)
            #pragma unroll
            for (int r = 0; r < 4; ++r) {
                int n = q0 + (2 * w + mi) * 16 + quad * 4 + r;   // >= 512
                int nn = n - 512;
                size_t rowb = ((size_t)bi * 1536 + nn) * EMB + h * HD;
                #pragma unroll
                for (int di = 0; di < 4; ++di)
                    Os[rowb + di * 16 + col] = accO[mi][di][r];
                if (col == 0)
                    ls[((size_t)bi * 1536 + nn) * NH + h] = lacc[mi][r];
            }
    }
}

// ---------------------------------------------------------------------------
// Kernel 3: combine partial slots for tokens n>=512, nc=(2*qb+9)>>3 slots,
// normalize, -> ao bf16.
// ---------------------------------------------------------------------------
__global__ __launch_bounds__(256) void combine_kernel(
    const float* __restrict__ Osp, const float* __restrict__ lsp,
    __hip_bfloat16* __restrict__ ao)
{
    const size_t SLOT = (size_t)2 * 1536 * EMB;
    const size_t LSLOT = (size_t)2 * 1536 * NH;
    size_t e8 = ((size_t)blockIdx.x * 256 + threadIdx.x) * 8;  // < 2,359,296
    int u = e8 / EMB;                 // 0..3071 (bi*1536 + nn)
    int within = e8 % EMB;
    int h = within >> 6;
    int bi = u / 1536, nn = u % 1536;
    int n = 512 + nn;
    int qb = n >> 7;                  // 4..15
    int nc = (2 * qb + 9) >> 3;       // 2..4
    float4 a0 = *(const float4*)&Osp[e8];
    float4 a1 = *(const float4*)&Osp[e8 + 4];
    float lsum = lsp[(size_t)u * NH + h];
    for (int cc = 1; cc < nc; ++cc) {
        const float* O = Osp + (size_t)cc * SLOT;
        float4 b0 = *(const float4*)&O[e8];
        float4 b1 = *(const float4*)&O[e8 + 4];
        a0.x += b0.x; a0.y += b0.y; a0.z += b0.z; a0.w += b0.w;
        a1.x += b1.x; a1.y += b1.y; a1.z += b1.z; a1.w += b1.w;
        lsum += lsp[(size_t)cc * LSLOT + (size_t)u * NH + h];
    }
    float inv = 1.0f / lsum;
    short8 o;
    o[0] = f2bf(a0.x * inv); o[1] = f2bf(a0.y * inv);
    o[2] = f2bf(a0.z * inv); o[3] = f2bf(a0.w * inv);
    o[4] = f2bf(a1.x * inv); o[5] = f2bf(a1.y * inv);
    o[6] = f2bf(a1.z * inv); o[7] = f2bf(a1.w * inv);
    *(short8*)&ao[((size_t)bi * SEQ + n) * EMB + within] = o;
}

// ---------------------------------------------------------------------------
// Kernel 4: output projection, 64x64 tiles -> 768 blocks (3.0 blocks/CU).
// gll16 staging, XOR swizzle.
// ---------------------------------------------------------------------------
__global__ __launch_bounds__(256) void out_proj_mfma_kernel(
    const __hip_bfloat16* __restrict__ a, const __hip_bfloat16* __restrict__ wob,
    const float* __restrict__ bias, float* __restrict__ out)
{
    __shared__ __align__(16) short As[64 * 64];
    __shared__ __align__(16) short Bs[64 * 64];
    const int t = threadIdx.x;
    const int w = t >> 6, lane = t & 63;
    const int col = lane & 15, quad = lane >> 4;
    const int wm = w >> 1, wn = w & 1;            // wave: 32 m x 32 n
    const int m0 = blockIdx.y * 64;
    const int n0 = blockIdx.x * 64;
    const short* A = (const short*)a;
    const short* W = (const short*)wob;

    float4v acc[2][2];
    #pragma unroll
    for (int mi = 0; mi < 2; ++mi)
        #pragma unroll
        for (int ni = 0; ni < 2; ++ni) acc[mi][ni] = (float4v){0.f, 0.f, 0.f, 0.f};

    for (int kb = 0; kb < EMB; kb += 64) {
        #pragma unroll
        for (int c = 0; c < 2; ++c) {
            int I = w * 128 + c * 64 + lane;      // 0..511
            int row = I >> 3;
            int c8 = (I & 7) ^ (row & 7);
            gll16(A + (size_t)(m0 + row) * EMB + kb + c8 * 8,
                  &As[(w * 128 + c * 64) * 8]);
            gll16(W + (size_t)(n0 + row) * EMB + kb + c8 * 8,
                  &Bs[(w * 128 + c * 64) * 8]);
        }
        __syncthreads();
        #pragma unroll
        for (int ks = 0; ks < 2; ++ks) {
            short8 av[2], bv[2];
            #pragma unroll
            for (int mi = 0; mi < 2; ++mi) {
                int row = wm * 32 + mi * 16 + col;
                av[mi] = *(short8*)&As[row * 64 + (((ks * 4 + quad) ^ (row & 7)) * 8)];
            }
            #pragma unroll
            for (int ni = 0; ni < 2; ++ni) {
                int row = wn * 32 + ni * 16 + col;
                bv[ni] = *(short8*)&Bs[row * 64 + (((ks * 4 + quad) ^ (row & 7)) * 8)];
            }
            #pragma unroll
            for (int mi = 0; mi < 2; ++mi)
                #pragma unroll
                for (int ni = 0; ni < 2; ++ni)
                    acc[mi][ni] = __builtin_amdgcn_mfma_f32_16x16x32_bf16(
                        av[mi], bv[ni], acc[mi][ni], 0, 0, 0);
        }
        __syncthreads();
    }
    #pragma unroll
    for (int mi = 0; mi < 2; ++mi)
        #pragma unroll
        for (int ni = 0; ni < 2; ++ni) {
            int gj = n0 + wn * 32 + ni * 16 + col;
            float bsv = bias[gj];
            #pragma unroll
            for (int r = 0; r < 4; ++r) {
                int gm = m0 + wm * 32 + mi * 16 + quad * 4 + r;
                out[(size_t)gm * EMB + gj] = acc[mi][ni][r] + bsv;
            }
        }
}

extern "C" void kernel_launch(void* const* d_in, const int* in_sizes, int n_in,
                              void* d_out, int out_size, void* d_ws, size_t ws_size,
                              hipStream_t stream) {
    const float* x  = (const float*)d_in[0];
    const float* wq = (const float*)d_in[1];
    const float* bq = (const float*)d_in[2];
    const float* wk = (const float*)d_in[3];
    const float* bk = (const float*)d_in[4];
    const float* wv = (const float*)d_in[5];
    const float* bv = (const float*)d_in[6];
    const float* wo = (const float*)d_in[7];
    const float* bo = (const float*)d_in[8];
    float* out = (float*)d_out;

    const size_t TOK = (size_t)NTOK * EMB;     // 3,145,728
    const size_t WSZ = (size_t)EMB * EMB;      //   589,824
    __hip_bfloat16* xb  = (__hip_bfloat16*)d_ws;
    __hip_bfloat16* wqb = xb  + TOK;
    __hip_bfloat16* wkb = wqb + WSZ;
    __hip_bfloat16* wvb = wkb + WSZ;
    __hip_bfloat16* wob = wvb + WSZ;
    __hip_bfloat16* qb  = wob + WSZ;
    __hip_bfloat16* kb  = qb  + TOK;
    __hip_bfloat16* vTb = kb  + TOK;
    __hip_bfloat16* aob = vTb + TOK;
    // fp32 partial slots (4 chunk slots) for tokens >= 512
    float* Osp = (float*)(aob + TOK);                       // 4*2*1536*768 fp32
    float* lsp = Osp + (size_t)4 * 2 * 1536 * EMB;          // 4*2*1536*12 fp32

    cast_kernel<<<2688, 256, 0, stream>>>(x, wq, wk, wv, wo, xb, wqb, wkb, wvb, wob);
    qkv_mfma_kernel<<<dim3(18, 64), 256, 0, stream>>>(xb, wqb, bq, wkb, bk, wvb, bv,
                                                      qb, kb, vTb);
    attn_mfma_kernel<<<960, 256, 0, stream>>>(qb, kb, vTb, aob, Osp, lsp);
    combine_kernel<<<1152, 256, 0, stream>>>(Osp, lsp, aob);
    out_proj_mfma_kernel<<<dim3(12, 64), 256, 0, stream>>>(aob, wob, bo, out);
}